// Round 2
// baseline (5094.640 us; speedup 1.0000x reference)
//
#include <hip/hip_runtime.h>

#define S_LEN 2048
#define NH 32
#define NKV 8
#define HEADD 64
#define DMODEL 2048
#define NQKV 3072

typedef float f32x4 __attribute__((ext_vector_type(4)));
typedef short s16x8 __attribute__((ext_vector_type(8)));
typedef int   i32x4 __attribute__((ext_vector_type(4)));
typedef unsigned short u16;
typedef u16 u16x4 __attribute__((ext_vector_type(4)));

__device__ __forceinline__ float b2f(u16 u) {
  unsigned int x = ((unsigned int)u) << 16;
  float f;
  __builtin_memcpy(&f, &x, 4);
  return f;
}
__device__ __forceinline__ u16 f2b(float f) {
  unsigned int x;
  __builtin_memcpy(&x, &f, 4);
  unsigned int r = x + 0x7fffu + ((x >> 16) & 1u);
  return (u16)(r >> 16);
}

// ---------- x fp32 -> bf16 ----------
__global__ void cast_x_kernel(const float* __restrict__ src, u16* __restrict__ dst) {
  int i = (blockIdx.x * 256 + threadIdx.x) * 4;
  f32x4 v = *(const f32x4*)(src + i);
  u16x4 o;
  o[0] = f2b(v[0]); o[1] = f2b(v[1]); o[2] = f2b(v[2]); o[3] = f2b(v[3]);
  *(u16x4*)(dst + i) = o;
}

// ---------- transpose + cast: src (K x N fp32) -> dst (N x K bf16) ----------
__global__ void transpose_cast(const float* __restrict__ src, u16* __restrict__ dst, int N, int K) {
  __shared__ float tile[32][33];
  int n0 = blockIdx.x * 32, k0 = blockIdx.y * 32;
  int tx = threadIdx.x, ty = threadIdx.y;  // (32, 8)
#pragma unroll
  for (int i = 0; i < 32; i += 8)
    tile[ty + i][tx] = src[(size_t)(k0 + ty + i) * N + n0 + tx];
  __syncthreads();
#pragma unroll
  for (int i = 0; i < 32; i += 8)
    dst[(size_t)(n0 + ty + i) * K + k0 + tx] = f2b(tile[tx][ty + i]);
}

// ---------- GEMM: C(MxN) = A(MxK,bf16) * Bt(NxK,bf16)^T (verified m92-pattern) ----------
#define LDW 40

__global__ __launch_bounds__(256) void gemm_bt(
    const u16* __restrict__ A, const u16* __restrict__ Bt, void* __restrict__ Cout,
    int M, int N, int K, int writeF32) {
  __shared__ __align__(16) u16 As[128 * LDW];
  __shared__ __align__(16) u16 Bs[128 * LDW];

  int nb = N >> 7;
  int m0 = (blockIdx.x / nb) << 7;
  int n0 = (blockIdx.x % nb) << 7;
  int tid = threadIdx.x;
  int lane = tid & 63;
  int wv = tid >> 6;
  int l15 = lane & 15;
  int quad = lane >> 4;
  int wm = (wv >> 1) << 6;
  int wn = (wv & 1) << 6;

  int sr = tid >> 2;
  int sc = (tid & 3) << 3;

  const u16* pa = A + (size_t)(m0 + sr) * K + sc;
  const u16* pb = Bt + (size_t)(n0 + sr) * K + sc;

  f32x4 acc[4][4] = {};

  for (int k0 = 0; k0 < K; k0 += 32) {
    i32x4 a1 = *(const i32x4*)(pa + k0);
    i32x4 a2 = *(const i32x4*)(pa + k0 + (size_t)64 * K);
    i32x4 b1 = *(const i32x4*)(pb + k0);
    i32x4 b2 = *(const i32x4*)(pb + k0 + (size_t)64 * K);
    __syncthreads();
    *(i32x4*)&As[sr * LDW + sc] = a1;
    *(i32x4*)&As[(sr + 64) * LDW + sc] = a2;
    *(i32x4*)&Bs[sr * LDW + sc] = b1;
    *(i32x4*)&Bs[(sr + 64) * LDW + sc] = b2;
    __syncthreads();
    s16x8 af[4], bf[4];
#pragma unroll
    for (int i = 0; i < 4; i++)
      af[i] = *(const s16x8*)&As[(wm + i * 16 + l15) * LDW + (quad << 3)];
#pragma unroll
    for (int i = 0; i < 4; i++)
      bf[i] = *(const s16x8*)&Bs[(wn + i * 16 + l15) * LDW + (quad << 3)];
#pragma unroll
    for (int mi = 0; mi < 4; mi++)
#pragma unroll
      for (int ni = 0; ni < 4; ni++)
        acc[mi][ni] = __builtin_amdgcn_mfma_f32_16x16x32_bf16(af[mi], bf[ni], acc[mi][ni], 0, 0, 0);
  }

#pragma unroll
  for (int mi = 0; mi < 4; mi++)
#pragma unroll
    for (int ni = 0; ni < 4; ni++)
#pragma unroll
      for (int r = 0; r < 4; r++) {
        int row = m0 + wm + mi * 16 + (quad << 2) + r;
        int col = n0 + wn + ni * 16 + l15;
        float v = acc[mi][ni][r];
        if (writeF32) ((float*)Cout)[(size_t)row * N + col] = v;
        else ((u16*)Cout)[(size_t)row * N + col] = f2b(v);
      }
}

// ---------- in-place RoPE on q (scaled by 0.125) and k ----------
__global__ void rope_kernel(u16* __restrict__ qkv) {
  int row = blockIdx.x;
  int s = row & (S_LEN - 1);
  u16* p = qkv + (size_t)row * NQKV;
  int t = threadIdx.x;
  int d = t & 31;
  int hh = t >> 5;
  float inv_freq = exp2f(-(float)d * (13.287712379549449f / 32.0f));
  float ang = (float)s * inv_freq;
  float sn, cs;
  sincosf(ang, &sn, &cs);
#pragma unroll
  for (int i = 0; i < 4; i++) {
    int base = (hh + (i << 3)) * HEADD + d;
    float x1 = b2f(p[base]);
    float x2 = b2f(p[base + 32]);
    p[base]      = f2b((x1 * cs - x2 * sn) * 0.125f);
    p[base + 32] = f2b((x1 * sn + x2 * cs) * 0.125f);
  }
  {
    int base = DMODEL + hh * HEADD + d;
    float x1 = b2f(p[base]);
    float x2 = b2f(p[base + 32]);
    p[base]      = f2b(x1 * cs - x2 * sn);
    p[base + 32] = f2b(x1 * sn + x2 * cs);
  }
}

// ---------- ISOLATION BUILD: by-construction-correct fp32 flash attention ----------
// block = one (b, h, s) query row; 256 threads = 64 dims x 4 key-groups.
__global__ __launch_bounds__(256) void attn_ref_kernel(const u16* __restrict__ qkv, u16* __restrict__ out) {
  __shared__ float qs[64];
  __shared__ float ps[256];
  __shared__ float red[4][72];
  __shared__ float mred[4], lred[4];

  int bid = blockIdx.x;
  int s  = bid & (S_LEN - 1);
  int bh = bid >> 11;
  int h = bh & 31;
  int b = bh >> 5;
  int g = h >> 2;
  int tid = threadIdx.x;
  int d = tid & 63, kg = tid >> 6;

  const u16* qrow = qkv + (size_t)(b * S_LEN + s) * NQKV + h * HEADD;
  if (tid < 64) qs[tid] = b2f(qrow[tid]);  // already rope'd + 0.125-scaled
  __syncthreads();

  float m = -3.0e38f, l = 0.f, acc = 0.f;
  const u16* kbase = qkv + (size_t)b * S_LEN * NQKV + DMODEL + g * HEADD;
  const u16* vbase = kbase + 512;

  for (int t0 = 0; t0 <= s; t0 += 256) {
    int nk = min(256, s + 1 - t0);
    float sc = -3.0e38f;
    if (tid < nk) {
      const u16* krow = kbase + (size_t)(t0 + tid) * NQKV;
      float a = 0.f;
#pragma unroll 8
      for (int dd = 0; dd < 64; dd++) a += qs[dd] * b2f(krow[dd]);
      sc = a;
    }
    float wmax = sc;
    for (int off = 32; off; off >>= 1) wmax = fmaxf(wmax, __shfl_xor(wmax, off));
    if ((tid & 63) == 0) mred[tid >> 6] = wmax;
    __syncthreads();
    float mt = fmaxf(fmaxf(mred[0], mred[1]), fmaxf(mred[2], mred[3]));
    float m_new = fmaxf(m, mt);
    float alpha = __expf(m - m_new);
    m = m_new;
    float p = (tid < nk) ? __expf(sc - m_new) : 0.f;
    ps[tid] = p;
    __syncthreads();
    acc *= alpha; l *= alpha;
    int j0 = kg * 64;
    int jend = min(j0 + 64, nk);
    for (int j = j0; j < jend; j++) {
      float pj = ps[j];
      l += pj;
      acc += pj * b2f(vbase[(size_t)(t0 + j) * NQKV + d]);
    }
    __syncthreads();
  }

  red[kg][d] = acc;
  if (d == 0) lred[kg] = l;
  __syncthreads();
  if (kg == 0) {
    float a = red[0][d] + red[1][d] + red[2][d] + red[3][d];
    float lt = lred[0] + lred[1] + lred[2] + lred[3];
    out[(size_t)(b * S_LEN + s) * DMODEL + h * HEADD + d] = f2b(a / lt);
  }
}

extern "C" void kernel_launch(void* const* d_in, const int* in_sizes, int n_in,
                              void* d_out, int out_size, void* d_ws, size_t ws_size,
                              hipStream_t stream) {
  const float* x  = (const float*)d_in[0];
  const float* wq = (const float*)d_in[1];
  const float* wk = (const float*)d_in[2];
  const float* wv = (const float*)d_in[3];
  const float* wo = (const float*)d_in[4];

  char* ws = (char*)d_ws;
  u16* xb    = (u16*)ws;                                   // 4096x2048 bf16 (16.8 MB)
  u16* wqkvT = (u16*)(ws + 16777216);                      // 3072x2048 (12.6 MB)
  u16* woT   = (u16*)(ws + 16777216 + 12582912);           // 2048x2048 (8.4 MB)
  u16* qkv   = (u16*)(ws + 16777216 + 12582912 + 8388608); // 4096x3072 (25.2 MB)
  u16* attnb = xb;  // reuse: xb dead after gemm1

  cast_x_kernel<<<8192, 256, 0, stream>>>(x, xb);
  dim3 tb(32, 8);
  transpose_cast<<<dim3(64, 64), tb, 0, stream>>>(wq, wqkvT, 2048, 2048);
  transpose_cast<<<dim3(16, 64), tb, 0, stream>>>(wk, wqkvT + (size_t)2048 * 2048, 512, 2048);
  transpose_cast<<<dim3(16, 64), tb, 0, stream>>>(wv, wqkvT + (size_t)2560 * 2048, 512, 2048);
  transpose_cast<<<dim3(64, 64), tb, 0, stream>>>(wo, woT, 2048, 2048);

  gemm_bt<<<768, 256, 0, stream>>>(xb, wqkvT, qkv, 4096, NQKV, 2048, 0);
  rope_kernel<<<4096, 256, 0, stream>>>(qkv);
  attn_ref_kernel<<<131072, 256, 0, stream>>>(qkv, attnb);
  gemm_bt<<<512, 256, 0, stream>>>(attnb, woT, d_out, 4096, 2048, 2048, 1);
}

// Round 3
// 481.818 us; speedup vs baseline: 10.5738x; 10.5738x over previous
//
#include <hip/hip_runtime.h>

#define S_LEN 2048
#define NH 32
#define NKV 8
#define HEADD 64
#define DMODEL 2048
#define NQKV 3072

typedef float f32x4 __attribute__((ext_vector_type(4)));
typedef short s16x8 __attribute__((ext_vector_type(8)));
typedef int   i32x4 __attribute__((ext_vector_type(4)));
typedef unsigned short u16;
typedef u16 u16x4 __attribute__((ext_vector_type(4)));

__device__ __forceinline__ float b2f(u16 u) {
  unsigned int x = ((unsigned int)u) << 16;
  float f;
  __builtin_memcpy(&f, &x, 4);
  return f;
}
__device__ __forceinline__ u16 f2b(float f) {
  unsigned int x;
  __builtin_memcpy(&x, &f, 4);
  unsigned int r = x + 0x7fffu + ((x >> 16) & 1u);
  return (u16)(r >> 16);
}

// ---------- x fp32 -> bf16 ----------
__global__ void cast_x_kernel(const float* __restrict__ src, u16* __restrict__ dst) {
  int i = (blockIdx.x * 256 + threadIdx.x) * 4;
  f32x4 v = *(const f32x4*)(src + i);
  u16x4 o;
  o[0] = f2b(v[0]); o[1] = f2b(v[1]); o[2] = f2b(v[2]); o[3] = f2b(v[3]);
  *(u16x4*)(dst + i) = o;
}

// ---------- transpose + cast: src (K x N fp32) -> dst (N x K bf16) ----------
__global__ void transpose_cast(const float* __restrict__ src, u16* __restrict__ dst, int N, int K) {
  __shared__ float tile[32][33];
  int n0 = blockIdx.x * 32, k0 = blockIdx.y * 32;
  int tx = threadIdx.x, ty = threadIdx.y;  // (32, 8)
#pragma unroll
  for (int i = 0; i < 32; i += 8)
    tile[ty + i][tx] = src[(size_t)(k0 + ty + i) * N + n0 + tx];
  __syncthreads();
#pragma unroll
  for (int i = 0; i < 32; i += 8)
    dst[(size_t)(n0 + ty + i) * K + k0 + tx] = f2b(tile[tx][ty + i]);
}

// ---------- GEMM: C(MxN) = A(MxK,bf16) * Bt(NxK,bf16)^T (verified m92-pattern) ----------
#define LDW 40

__global__ __launch_bounds__(256) void gemm_bt(
    const u16* __restrict__ A, const u16* __restrict__ Bt, void* __restrict__ Cout,
    int M, int N, int K, int writeF32) {
  __shared__ __align__(16) u16 As[128 * LDW];
  __shared__ __align__(16) u16 Bs[128 * LDW];

  int nb = N >> 7;
  int m0 = (blockIdx.x / nb) << 7;
  int n0 = (blockIdx.x % nb) << 7;
  int tid = threadIdx.x;
  int lane = tid & 63;
  int wv = tid >> 6;
  int l15 = lane & 15;
  int quad = lane >> 4;
  int wm = (wv >> 1) << 6;
  int wn = (wv & 1) << 6;

  int sr = tid >> 2;
  int sc = (tid & 3) << 3;

  const u16* pa = A + (size_t)(m0 + sr) * K + sc;
  const u16* pb = Bt + (size_t)(n0 + sr) * K + sc;

  f32x4 acc[4][4] = {};

  for (int k0 = 0; k0 < K; k0 += 32) {
    i32x4 a1 = *(const i32x4*)(pa + k0);
    i32x4 a2 = *(const i32x4*)(pa + k0 + (size_t)64 * K);
    i32x4 b1 = *(const i32x4*)(pb + k0);
    i32x4 b2 = *(const i32x4*)(pb + k0 + (size_t)64 * K);
    __syncthreads();
    *(i32x4*)&As[sr * LDW + sc] = a1;
    *(i32x4*)&As[(sr + 64) * LDW + sc] = a2;
    *(i32x4*)&Bs[sr * LDW + sc] = b1;
    *(i32x4*)&Bs[(sr + 64) * LDW + sc] = b2;
    __syncthreads();
    s16x8 af[4], bf[4];
#pragma unroll
    for (int i = 0; i < 4; i++)
      af[i] = *(const s16x8*)&As[(wm + i * 16 + l15) * LDW + (quad << 3)];
#pragma unroll
    for (int i = 0; i < 4; i++)
      bf[i] = *(const s16x8*)&Bs[(wn + i * 16 + l15) * LDW + (quad << 3)];
#pragma unroll
    for (int mi = 0; mi < 4; mi++)
#pragma unroll
      for (int ni = 0; ni < 4; ni++)
        acc[mi][ni] = __builtin_amdgcn_mfma_f32_16x16x32_bf16(af[mi], bf[ni], acc[mi][ni], 0, 0, 0);
  }

#pragma unroll
  for (int mi = 0; mi < 4; mi++)
#pragma unroll
    for (int ni = 0; ni < 4; ni++)
#pragma unroll
      for (int r = 0; r < 4; r++) {
        int row = m0 + wm + mi * 16 + (quad << 2) + r;
        int col = n0 + wn + ni * 16 + l15;
        float v = acc[mi][ni][r];
        if (writeF32) ((float*)Cout)[(size_t)row * N + col] = v;
        else ((u16*)Cout)[(size_t)row * N + col] = f2b(v);
      }
}

// ---------- in-place RoPE on q (scaled by 0.125) and k ----------
__global__ void rope_kernel(u16* __restrict__ qkv) {
  int row = blockIdx.x;
  int s = row & (S_LEN - 1);
  u16* p = qkv + (size_t)row * NQKV;
  int t = threadIdx.x;
  int d = t & 31;
  int hh = t >> 5;
  float inv_freq = exp2f(-(float)d * (13.287712379549449f / 32.0f));
  float ang = (float)s * inv_freq;
  float sn, cs;
  sincosf(ang, &sn, &cs);
#pragma unroll
  for (int i = 0; i < 4; i++) {
    int base = (hh + (i << 3)) * HEADD + d;
    float x1 = b2f(p[base]);
    float x2 = b2f(p[base + 32]);
    p[base]      = f2b((x1 * cs - x2 * sn) * 0.125f);
    p[base + 32] = f2b((x1 * sn + x2 * cs) * 0.125f);
  }
  {
    int base = DMODEL + hh * HEADD + d;
    float x1 = b2f(p[base]);
    float x2 = b2f(p[base + 32]);
    p[base]      = f2b(x1 * cs - x2 * sn);
    p[base + 32] = f2b(x1 * sn + x2 * cs);
  }
}

// ---------- MFMA flash attention: block = (b, kv-head, 32 q rows), 4 waves = 4 rep heads ----------
__global__ __launch_bounds__(256) void attn_kernel(const u16* __restrict__ qkv, u16* __restrict__ out) {
  __shared__ __align__(16) u16 Ks[32 * 72];
  __shared__ __align__(16) u16 Vs[32 * 66];
  __shared__ __align__(16) float Pb[4][16 * 36];

  int bid = blockIdx.x;
  int qb = bid & 63;
  int bg = bid >> 6;
  int g = bg & 7;
  int b = bg >> 3;
  int wv = threadIdx.x >> 6;
  int lane = threadIdx.x & 63;
  int l15 = lane & 15;
  int quad = lane >> 4;
  int h = (g << 2) + wv;
  int q0 = qb << 5;

  s16x8 qf[2][2];
#pragma unroll
  for (int qt = 0; qt < 2; qt++)
#pragma unroll
    for (int dh = 0; dh < 2; dh++)
      qf[qt][dh] = *(const s16x8*)(qkv + (size_t)(b * S_LEN + q0 + qt * 16 + l15) * NQKV +
                                   h * HEADD + dh * 32 + (quad << 3));

  float m_i[2] = {-1e30f, -1e30f};
  float l_i[2] = {0.f, 0.f};
  f32x4 acc[2][4] = {};

  int sr = threadIdx.x >> 3;
  int sc = (threadIdx.x & 7) << 3;

  for (int kb = 0; kb <= qb; kb++) {
    __syncthreads();
    {
      const u16* krow = qkv + (size_t)(b * S_LEN + kb * 32 + sr) * NQKV + DMODEL + g * HEADD + sc;
      *(i32x4*)&Ks[sr * 72 + sc] = *(const i32x4*)krow;
      i32x4 vvv = *(const i32x4*)(krow + 512);
      unsigned int* vw = (unsigned int*)&vvv;
      unsigned int* dw = (unsigned int*)&Vs[sr * 66 + sc];
#pragma unroll
      for (int j = 0; j < 4; j++) dw[j] = vw[j];
    }
    __syncthreads();

    s16x8 kf[2][2];
#pragma unroll
    for (int kt = 0; kt < 2; kt++)
#pragma unroll
      for (int dh = 0; dh < 2; dh++)
        kf[kt][dh] = *(const s16x8*)&Ks[(kt * 16 + l15) * 72 + dh * 32 + (quad << 3)];
    s16x8 vf[4];
#pragma unroll
    for (int ni = 0; ni < 4; ni++)
#pragma unroll
      for (int j = 0; j < 8; j++)
        vf[ni][j] = (short)Vs[((quad << 3) + j) * 66 + ni * 16 + l15];

    int last = (kb == qb);

#pragma unroll
    for (int qt = 0; qt < 2; qt++) {
      f32x4 sa[2] = {};
#pragma unroll
      for (int kt = 0; kt < 2; kt++)
#pragma unroll
        for (int dh = 0; dh < 2; dh++)
          sa[kt] = __builtin_amdgcn_mfma_f32_16x16x32_bf16(kf[kt][dh], qf[qt][dh], sa[kt], 0, 0, 0);

      float sv[8];
#pragma unroll
      for (int kt = 0; kt < 2; kt++)
#pragma unroll
        for (int r = 0; r < 4; r++) sv[kt * 4 + r] = sa[kt][r];

      if (last) {
        int qg = q0 + qt * 16 + l15;
#pragma unroll
        for (int kt = 0; kt < 2; kt++)
#pragma unroll
          for (int r = 0; r < 4; r++) {
            int kg = kb * 32 + kt * 16 + (quad << 2) + r;
            if (kg > qg) sv[kt * 4 + r] = -1e30f;
          }
      }

      float mx = sv[0];
#pragma unroll
      for (int i = 1; i < 8; i++) mx = fmaxf(mx, sv[i]);
      mx = fmaxf(mx, __shfl_xor(mx, 16));
      mx = fmaxf(mx, __shfl_xor(mx, 32));
      float m_new = fmaxf(m_i[qt], mx);
      float alpha = __expf(m_i[qt] - m_new);
      m_i[qt] = m_new;
      float ps = 0.f;
#pragma unroll
      for (int i = 0; i < 8; i++) { sv[i] = __expf(sv[i] - m_new); ps += sv[i]; }
      ps += __shfl_xor(ps, 16);
      ps += __shfl_xor(ps, 32);
      l_i[qt] = l_i[qt] * alpha + ps;

      // P round-trip through LDS (C-layout -> A-operand layout)
#pragma unroll
      for (int kt = 0; kt < 2; kt++)
#pragma unroll
        for (int r = 0; r < 4; r++)
          Pb[wv][l15 * 36 + kt * 16 + (quad << 2) + r] = sv[kt * 4 + r];

      // ensure cross-lane LDS writes are complete & not compiler-reordered
      asm volatile("s_waitcnt lgkmcnt(0)" ::: "memory");

      float af[4];
#pragma unroll
      for (int r = 0; r < 4; r++) af[r] = __shfl(alpha, (quad << 2) + r);
#pragma unroll
      for (int ni = 0; ni < 4; ni++)
#pragma unroll
        for (int r = 0; r < 4; r++) acc[qt][ni][r] *= af[r];

      f32x4 p0 = *(const f32x4*)&Pb[wv][l15 * 36 + (quad << 3)];
      f32x4 p1 = *(const f32x4*)&Pb[wv][l15 * 36 + (quad << 3) + 4];
      s16x8 pf;
#pragma unroll
      for (int j = 0; j < 4; j++) { pf[j] = (short)f2b(p0[j]); pf[j + 4] = (short)f2b(p1[j]); }

#pragma unroll
      for (int ni = 0; ni < 4; ni++)
        acc[qt][ni] = __builtin_amdgcn_mfma_f32_16x16x32_bf16(pf, vf[ni], acc[qt][ni], 0, 0, 0);
    }
  }

#pragma unroll
  for (int qt = 0; qt < 2; qt++) {
    float linv = 1.0f / l_i[qt];
    float lr[4];
#pragma unroll
    for (int r = 0; r < 4; r++) lr[r] = __shfl(linv, (quad << 2) + r);
#pragma unroll
    for (int ni = 0; ni < 4; ni++)
#pragma unroll
      for (int r = 0; r < 4; r++) {
        int srow = q0 + qt * 16 + (quad << 2) + r;
        out[(size_t)(b * S_LEN + srow) * DMODEL + h * HEADD + ni * 16 + l15] =
            f2b(acc[qt][ni][r] * lr[r]);
      }
  }
}

extern "C" void kernel_launch(void* const* d_in, const int* in_sizes, int n_in,
                              void* d_out, int out_size, void* d_ws, size_t ws_size,
                              hipStream_t stream) {
  const float* x  = (const float*)d_in[0];
  const float* wq = (const float*)d_in[1];
  const float* wk = (const float*)d_in[2];
  const float* wv = (const float*)d_in[3];
  const float* wo = (const float*)d_in[4];

  char* ws = (char*)d_ws;
  u16* xb    = (u16*)ws;                                   // 4096x2048 bf16 (16.8 MB)
  u16* wqkvT = (u16*)(ws + 16777216);                      // 3072x2048 (12.6 MB)
  u16* woT   = (u16*)(ws + 16777216 + 12582912);           // 2048x2048 (8.4 MB)
  u16* qkv   = (u16*)(ws + 16777216 + 12582912 + 8388608); // 4096x3072 (25.2 MB)
  u16* attnb = xb;  // reuse: xb dead after gemm1 — keeps ws usage at 62.9 MB (proven in-budget)

  cast_x_kernel<<<8192, 256, 0, stream>>>(x, xb);
  dim3 tb(32, 8);
  transpose_cast<<<dim3(64, 64), tb, 0, stream>>>(wq, wqkvT, 2048, 2048);
  transpose_cast<<<dim3(16, 64), tb, 0, stream>>>(wk, wqkvT + (size_t)2048 * 2048, 512, 2048);
  transpose_cast<<<dim3(16, 64), tb, 0, stream>>>(wv, wqkvT + (size_t)2560 * 2048, 512, 2048);
  transpose_cast<<<dim3(64, 64), tb, 0, stream>>>(wo, woT, 2048, 2048);

  gemm_bt<<<768, 256, 0, stream>>>(xb, wqkvT, qkv, 4096, NQKV, 2048, 0);
  rope_kernel<<<4096, 256, 0, stream>>>(qkv);
  attn_kernel<<<1024, 256, 0, stream>>>(qkv, attnb);
  gemm_bt<<<512, 256, 0, stream>>>(attnb, woT, d_out, 4096, 2048, 2048, 1);
}

// Round 4
// 392.786 us; speedup vs baseline: 12.9705x; 1.2267x over previous
//
#include <hip/hip_runtime.h>

#define S_LEN 2048
#define NH 32
#define NKV 8
#define HEADD 64
#define DMODEL 2048
#define NQKV 3072

typedef float f32x4 __attribute__((ext_vector_type(4)));
typedef short s16x8 __attribute__((ext_vector_type(8)));
typedef int   i32x4 __attribute__((ext_vector_type(4)));
typedef unsigned short u16;
typedef u16 u16x4 __attribute__((ext_vector_type(4)));

__device__ __forceinline__ float b2f(u16 u) {
  unsigned int x = ((unsigned int)u) << 16;
  float f;
  __builtin_memcpy(&f, &x, 4);
  return f;
}
__device__ __forceinline__ u16 f2b(float f) {
  unsigned int x;
  __builtin_memcpy(&x, &f, 4);
  unsigned int r = x + 0x7fffu + ((x >> 16) & 1u);
  return (u16)(r >> 16);
}

// async 16B/lane global -> LDS (lds dest = wave-uniform base + lane*16)
__device__ __forceinline__ void gload_lds16(const u16* g, u16* l) {
  __builtin_amdgcn_global_load_lds((const __attribute__((address_space(1))) void*)g,
                                   (__attribute__((address_space(3))) void*)l, 16, 0, 0);
}

// ---------- x fp32 -> bf16 ----------
__global__ void cast_x_kernel(const float* __restrict__ src, u16* __restrict__ dst) {
  int i = (blockIdx.x * 256 + threadIdx.x) * 4;
  f32x4 v = *(const f32x4*)(src + i);
  u16x4 o;
  o[0] = f2b(v[0]); o[1] = f2b(v[1]); o[2] = f2b(v[2]); o[3] = f2b(v[3]);
  *(u16x4*)(dst + i) = o;
}

// ---------- transpose + cast: src (K x N fp32) -> dst (N x K bf16) ----------
__global__ void transpose_cast(const float* __restrict__ src, u16* __restrict__ dst, int N, int K) {
  __shared__ float tile[32][33];
  int n0 = blockIdx.x * 32, k0 = blockIdx.y * 32;
  int tx = threadIdx.x, ty = threadIdx.y;  // (32, 8)
#pragma unroll
  for (int i = 0; i < 32; i += 8)
    tile[ty + i][tx] = src[(size_t)(k0 + ty + i) * N + n0 + tx];
  __syncthreads();
#pragma unroll
  for (int i = 0; i < 32; i += 8)
    dst[(size_t)(n0 + ty + i) * K + k0 + tx] = f2b(tile[tx][ty + i]);
}

// ---------- GEMM (m97-style): C(MxN) = A(MxK,bf16) * Bt(NxK,bf16)^T ----------
__global__ __launch_bounds__(256) void gemm_bt(
    const u16* __restrict__ A, const u16* __restrict__ Bt, void* __restrict__ Cout,
    int M, int N, int K, int writeF32) {
  __shared__ __align__(16) u16 As[128 * 32];  // unpadded: global_load_lds needs contiguity
  __shared__ __align__(16) u16 Bs[128 * 32];

  int nb = N >> 7;
  int m0 = (blockIdx.x / nb) << 7;
  int n0 = (blockIdx.x % nb) << 7;
  int tid = threadIdx.x;
  int lane = tid & 63;
  int w4 = tid >> 6;
  int l15 = lane & 15;
  int quad = lane >> 4;
  int wm = (w4 >> 1) << 6;
  int wn = (w4 & 1) << 6;

  // staging: wave w covers rows [w*32, w*32+32), lane i -> row w*32+16c+(i>>2), col (i&3)*8
  const u16* gA0 = A  + (size_t)(m0 + w4 * 32 + (lane >> 2)) * K + ((lane & 3) << 3);
  const u16* gA1 = gA0 + (size_t)16 * K;
  const u16* gB0 = Bt + (size_t)(n0 + w4 * 32 + (lane >> 2)) * K + ((lane & 3) << 3);
  const u16* gB1 = gB0 + (size_t)16 * K;
  u16* lA0 = &As[w4 * 1024];
  u16* lA1 = &As[w4 * 1024 + 512];
  u16* lB0 = &Bs[w4 * 1024];
  u16* lB1 = &Bs[w4 * 1024 + 512];

  f32x4 acc[4][4] = {};

  for (int k0 = 0; k0 < K; k0 += 32) {
    __syncthreads();  // previous iter's ds_reads complete before overwrite
    gload_lds16(gA0 + k0, lA0);
    gload_lds16(gA1 + k0, lA1);
    gload_lds16(gB0 + k0, lB0);
    gload_lds16(gB1 + k0, lB1);
    __syncthreads();  // compiler drains vmcnt before s_barrier -> LDS visible

    s16x8 af[4], bf[4];
#pragma unroll
    for (int i = 0; i < 4; i++)
      af[i] = *(const s16x8*)&As[(wm + i * 16 + l15) * 32 + (quad << 3)];
#pragma unroll
    for (int i = 0; i < 4; i++)
      bf[i] = *(const s16x8*)&Bs[(wn + i * 16 + l15) * 32 + (quad << 3)];
#pragma unroll
    for (int mi = 0; mi < 4; mi++)
#pragma unroll
      for (int ni = 0; ni < 4; ni++)
        acc[mi][ni] = __builtin_amdgcn_mfma_f32_16x16x32_bf16(af[mi], bf[ni], acc[mi][ni], 0, 0, 0);
  }

#pragma unroll
  for (int mi = 0; mi < 4; mi++)
#pragma unroll
    for (int ni = 0; ni < 4; ni++)
#pragma unroll
      for (int r = 0; r < 4; r++) {
        int row = m0 + wm + mi * 16 + (quad << 2) + r;
        int col = n0 + wn + ni * 16 + l15;
        float v = acc[mi][ni][r];
        if (writeF32) ((float*)Cout)[(size_t)row * N + col] = v;
        else ((u16*)Cout)[(size_t)row * N + col] = f2b(v);
      }
}

// ---------- in-place RoPE on q (scaled by 0.125) and k ----------
__global__ void rope_kernel(u16* __restrict__ qkv) {
  int row = blockIdx.x;
  int s = row & (S_LEN - 1);
  u16* p = qkv + (size_t)row * NQKV;
  int t = threadIdx.x;
  int d = t & 31;
  int hh = t >> 5;
  float inv_freq = exp2f(-(float)d * (13.287712379549449f / 32.0f));
  float ang = (float)s * inv_freq;
  float sn, cs;
  sincosf(ang, &sn, &cs);
#pragma unroll
  for (int i = 0; i < 4; i++) {
    int base = (hh + (i << 3)) * HEADD + d;
    float x1 = b2f(p[base]);
    float x2 = b2f(p[base + 32]);
    p[base]      = f2b((x1 * cs - x2 * sn) * 0.125f);
    p[base + 32] = f2b((x1 * sn + x2 * cs) * 0.125f);
  }
  {
    int base = DMODEL + hh * HEADD + d;
    float x1 = b2f(p[base]);
    float x2 = b2f(p[base + 32]);
    p[base]      = f2b(x1 * cs - x2 * sn);
    p[base + 32] = f2b(x1 * sn + x2 * cs);
  }
}

// ---------- V transpose: qkv v-slice -> Vt[b][g][d=64][s=2048] ----------
__global__ void vtrans_kernel(const u16* __restrict__ qkv, u16* __restrict__ Vt) {
  __shared__ __align__(16) u16 tile[64][72];
  int bid = blockIdx.x;  // 2*8*32 = 512
  int st = bid & 31;
  int g  = (bid >> 5) & 7;
  int b  = bid >> 8;
  int tid = threadIdx.x;
  int r = tid >> 2;             // 0..63
  int c = (tid & 3) << 4;       // 0,16,32,48
  const u16* src = qkv + (size_t)(b * S_LEN + st * 64 + r) * NQKV + 2560 + g * 64 + c;
  *(i32x4*)&tile[r][c]     = *(const i32x4*)src;
  *(i32x4*)&tile[r][c + 8] = *(const i32x4*)(src + 8);
  __syncthreads();
  u16* dst = Vt + (size_t)((b * 8 + g) * 64 + r) * S_LEN + st * 64 + c;
  u16 tmp[16];
#pragma unroll
  for (int j = 0; j < 16; j++) tmp[j] = tile[c + j][r];
  *(i32x4*)dst       = *(i32x4*)&tmp[0];
  *(i32x4*)(dst + 8) = *(i32x4*)&tmp[8];
}

// ---------- MFMA flash attention, barrier-free k-loop ----------
// block = (b, g, qb); 4 waves = 4 rep heads; K/V frags direct from global (L1/L2 shared)
__global__ __launch_bounds__(256) void attn_kernel(const u16* __restrict__ qkv,
                                                   const u16* __restrict__ Vt,
                                                   u16* __restrict__ out) {
  __shared__ __align__(16) float Pb[4][16 * 36];

  int bid = blockIdx.x;
  int bg = bid & 15;           // (b,g) in low bits: the 16 longest blocks launch first
  int qb = 63 - (bid >> 4);    // descending qb => short blocks backfill the tail
  int g = bg & 7;
  int b = bg >> 3;
  int wv = threadIdx.x >> 6;
  int lane = threadIdx.x & 63;
  int l15 = lane & 15;
  int quad = lane >> 4;
  int h = (g << 2) + wv;
  int q0 = qb << 5;

  s16x8 qf[2][2];
#pragma unroll
  for (int qt = 0; qt < 2; qt++)
#pragma unroll
    for (int dh = 0; dh < 2; dh++)
      qf[qt][dh] = *(const s16x8*)(qkv + (size_t)(b * S_LEN + q0 + qt * 16 + l15) * NQKV +
                                   h * HEADD + dh * 32 + (quad << 3));

  float m_i[2] = {-1e30f, -1e30f};
  float l_i[2] = {0.f, 0.f};
  f32x4 acc[2][4] = {};

  const u16* kp0 = qkv + (size_t)b * S_LEN * NQKV + DMODEL + g * HEADD +
                   (size_t)l15 * NQKV + (quad << 3);
  const u16* vp0 = Vt + (size_t)((b * 8 + g) * 64 + l15) * S_LEN + (quad << 3);

  s16x8 kfa[2][2], vfa[4], kfb[2][2], vfb[4];

  auto loadkv = [&](int kb, s16x8 (&kf)[2][2], s16x8 (&vf)[4]) {
    const u16* kp = kp0 + (size_t)kb * 32 * NQKV;
    kf[0][0] = *(const s16x8*)kp;
    kf[0][1] = *(const s16x8*)(kp + 32);
    kf[1][0] = *(const s16x8*)(kp + (size_t)16 * NQKV);
    kf[1][1] = *(const s16x8*)(kp + (size_t)16 * NQKV + 32);
    const u16* vp = vp0 + kb * 32;
    vf[0] = *(const s16x8*)vp;
    vf[1] = *(const s16x8*)(vp + 16 * S_LEN);
    vf[2] = *(const s16x8*)(vp + 32 * S_LEN);
    vf[3] = *(const s16x8*)(vp + 48 * S_LEN);
  };

  auto compute = [&](int kb, s16x8 (&kf)[2][2], s16x8 (&vf)[4]) {
    int last = (kb == qb);
#pragma unroll
    for (int qt = 0; qt < 2; qt++) {
      f32x4 sa[2] = {};
#pragma unroll
      for (int kt = 0; kt < 2; kt++)
#pragma unroll
        for (int dh = 0; dh < 2; dh++)
          sa[kt] = __builtin_amdgcn_mfma_f32_16x16x32_bf16(kf[kt][dh], qf[qt][dh], sa[kt], 0, 0, 0);

      float sv[8];
#pragma unroll
      for (int kt = 0; kt < 2; kt++)
#pragma unroll
        for (int r = 0; r < 4; r++) sv[kt * 4 + r] = sa[kt][r];

      if (last) {
        int qg = q0 + qt * 16 + l15;
#pragma unroll
        for (int kt = 0; kt < 2; kt++)
#pragma unroll
          for (int r = 0; r < 4; r++) {
            int kg = kb * 32 + kt * 16 + (quad << 2) + r;
            if (kg > qg) sv[kt * 4 + r] = -1e30f;
          }
      }

      float mx = sv[0];
#pragma unroll
      for (int i = 1; i < 8; i++) mx = fmaxf(mx, sv[i]);
      mx = fmaxf(mx, __shfl_xor(mx, 16));
      mx = fmaxf(mx, __shfl_xor(mx, 32));
      float m_new = fmaxf(m_i[qt], mx);
      float alpha = __expf(m_i[qt] - m_new);
      m_i[qt] = m_new;
      float ps = 0.f;
#pragma unroll
      for (int i = 0; i < 8; i++) { sv[i] = __expf(sv[i] - m_new); ps += sv[i]; }
      ps += __shfl_xor(ps, 16);
      ps += __shfl_xor(ps, 32);
      l_i[qt] = l_i[qt] * alpha + ps;

      // P round-trip through per-wave LDS (C-layout -> A-operand layout)
#pragma unroll
      for (int kt = 0; kt < 2; kt++)
#pragma unroll
        for (int r = 0; r < 4; r++)
          Pb[wv][l15 * 36 + kt * 16 + (quad << 2) + r] = sv[kt * 4 + r];

      asm volatile("s_waitcnt lgkmcnt(0)" ::: "memory");

      float af[4];
#pragma unroll
      for (int r = 0; r < 4; r++) af[r] = __shfl(alpha, (quad << 2) + r);
#pragma unroll
      for (int ni = 0; ni < 4; ni++)
#pragma unroll
        for (int r = 0; r < 4; r++) acc[qt][ni][r] *= af[r];

      f32x4 p0 = *(const f32x4*)&Pb[wv][l15 * 36 + (quad << 3)];
      f32x4 p1 = *(const f32x4*)&Pb[wv][l15 * 36 + (quad << 3) + 4];
      s16x8 pf;
#pragma unroll
      for (int j = 0; j < 4; j++) { pf[j] = (short)f2b(p0[j]); pf[j + 4] = (short)f2b(p1[j]); }

#pragma unroll
      for (int ni = 0; ni < 4; ni++)
        acc[qt][ni] = __builtin_amdgcn_mfma_f32_16x16x32_bf16(pf, vf[ni], acc[qt][ni], 0, 0, 0);
    }
  };

  loadkv(0, kfa, vfa);
  int kb = 0;
  while (true) {
    if (kb < qb) loadkv(kb + 1, kfb, vfb);
    compute(kb, kfa, vfa);
    kb++;
    if (kb > qb) break;
    if (kb < qb) loadkv(kb + 1, kfa, vfa);
    compute(kb, kfb, vfb);
    kb++;
    if (kb > qb) break;
  }

#pragma unroll
  for (int qt = 0; qt < 2; qt++) {
    float linv = 1.0f / l_i[qt];
    float lr[4];
#pragma unroll
    for (int r = 0; r < 4; r++) lr[r] = __shfl(linv, (quad << 2) + r);
#pragma unroll
    for (int ni = 0; ni < 4; ni++)
#pragma unroll
      for (int r = 0; r < 4; r++) {
        int srow = q0 + qt * 16 + (quad << 2) + r;
        out[(size_t)(b * S_LEN + srow) * DMODEL + h * HEADD + ni * 16 + l15] =
            f2b(acc[qt][ni][r] * lr[r]);
      }
  }
}

extern "C" void kernel_launch(void* const* d_in, const int* in_sizes, int n_in,
                              void* d_out, int out_size, void* d_ws, size_t ws_size,
                              hipStream_t stream) {
  const float* x  = (const float*)d_in[0];
  const float* wq = (const float*)d_in[1];
  const float* wk = (const float*)d_in[2];
  const float* wv = (const float*)d_in[3];
  const float* wo = (const float*)d_in[4];

  char* ws = (char*)d_ws;
  u16* xb    = (u16*)ws;                                   // 4096x2048 bf16 (16.8 MB)
  u16* wqkvT = (u16*)(ws + 16777216);                      // 3072x2048 (12.6 MB)
  u16* woT   = (u16*)(ws + 16777216 + 12582912);           // 2048x2048 (8.4 MB)
  u16* qkv   = (u16*)(ws + 16777216 + 12582912 + 8388608); // 4096x3072 (25.2 MB)
  u16* attnb = xb;     // xb dead after gemm1
  u16* Vt    = wqkvT;  // wqkvT dead after gemm1 (4.2 MB needed) — peak ws stays 62.9 MB

  cast_x_kernel<<<8192, 256, 0, stream>>>(x, xb);
  dim3 tb(32, 8);
  transpose_cast<<<dim3(64, 64), tb, 0, stream>>>(wq, wqkvT, 2048, 2048);
  transpose_cast<<<dim3(16, 64), tb, 0, stream>>>(wk, wqkvT + (size_t)2048 * 2048, 512, 2048);
  transpose_cast<<<dim3(16, 64), tb, 0, stream>>>(wv, wqkvT + (size_t)2560 * 2048, 512, 2048);
  transpose_cast<<<dim3(64, 64), tb, 0, stream>>>(wo, woT, 2048, 2048);

  gemm_bt<<<768, 256, 0, stream>>>(xb, wqkvT, qkv, 4096, NQKV, 2048, 0);
  rope_kernel<<<4096, 256, 0, stream>>>(qkv);
  vtrans_kernel<<<512, 256, 0, stream>>>(qkv, Vt);
  attn_kernel<<<1024, 256, 0, stream>>>(qkv, Vt, attnb);
  gemm_bt<<<512, 256, 0, stream>>>(attnb, woT, d_out, 4096, 2048, 2048, 1);
}

// Round 5
// 388.354 us; speedup vs baseline: 13.1186x; 1.0114x over previous
//
#include <hip/hip_runtime.h>

#define S_LEN 2048
#define NH 32
#define NKV 8
#define HEADD 64
#define DMODEL 2048
#define NQKV 3072

typedef float f32x4 __attribute__((ext_vector_type(4)));
typedef float f32x16 __attribute__((ext_vector_type(16)));
typedef short s16x8 __attribute__((ext_vector_type(8)));
typedef int   i32x4 __attribute__((ext_vector_type(4)));
typedef unsigned short u16;
typedef u16 u16x4 __attribute__((ext_vector_type(4)));

__device__ __forceinline__ float b2f(u16 u) {
  unsigned int x = ((unsigned int)u) << 16;
  float f;
  __builtin_memcpy(&f, &x, 4);
  return f;
}
__device__ __forceinline__ u16 f2b(float f) {
  unsigned int x;
  __builtin_memcpy(&x, &f, 4);
  unsigned int r = x + 0x7fffu + ((x >> 16) & 1u);
  return (u16)(r >> 16);
}
__device__ __forceinline__ unsigned fbits(float f) {
  unsigned x; __builtin_memcpy(&x, &f, 4); return x;
}

// async 16B/lane global -> LDS
__device__ __forceinline__ void gload_lds16(const u16* g, u16* l) {
  __builtin_amdgcn_global_load_lds((const __attribute__((address_space(1))) void*)g,
                                   (__attribute__((address_space(3))) void*)l, 16, 0, 0);
}

// ---------- x fp32 -> bf16 ----------
__global__ void cast_x_kernel(const float* __restrict__ src, u16* __restrict__ dst) {
  int i = (blockIdx.x * 256 + threadIdx.x) * 4;
  f32x4 v = *(const f32x4*)(src + i);
  u16x4 o;
  o[0] = f2b(v[0]); o[1] = f2b(v[1]); o[2] = f2b(v[2]); o[3] = f2b(v[3]);
  *(u16x4*)(dst + i) = o;
}

// ---------- transpose + cast: src (K x N fp32) -> dst (N x K bf16) ----------
__global__ void transpose_cast(const float* __restrict__ src, u16* __restrict__ dst, int N, int K) {
  __shared__ float tile[32][33];
  int n0 = blockIdx.x * 32, k0 = blockIdx.y * 32;
  int tx = threadIdx.x, ty = threadIdx.y;  // (32, 8)
#pragma unroll
  for (int i = 0; i < 32; i += 8)
    tile[ty + i][tx] = src[(size_t)(k0 + ty + i) * N + n0 + tx];
  __syncthreads();
#pragma unroll
  for (int i = 0; i < 32; i += 8)
    dst[(size_t)(n0 + ty + i) * K + k0 + tx] = f2b(tile[tx][ty + i]);
}

// ---------- GEMM (m97-style): C(MxN) = A(MxK,bf16) * Bt(NxK,bf16)^T ----------
__global__ __launch_bounds__(256) void gemm_bt(
    const u16* __restrict__ A, const u16* __restrict__ Bt, void* __restrict__ Cout,
    int M, int N, int K, int writeF32) {
  __shared__ __align__(16) u16 As[128 * 32];
  __shared__ __align__(16) u16 Bs[128 * 32];

  int nb = N >> 7;
  int m0 = (blockIdx.x / nb) << 7;
  int n0 = (blockIdx.x % nb) << 7;
  int tid = threadIdx.x;
  int lane = tid & 63;
  int w4 = tid >> 6;
  int l15 = lane & 15;
  int quad = lane >> 4;
  int wm = (w4 >> 1) << 6;
  int wn = (w4 & 1) << 6;

  const u16* gA0 = A  + (size_t)(m0 + w4 * 32 + (lane >> 2)) * K + ((lane & 3) << 3);
  const u16* gA1 = gA0 + (size_t)16 * K;
  const u16* gB0 = Bt + (size_t)(n0 + w4 * 32 + (lane >> 2)) * K + ((lane & 3) << 3);
  const u16* gB1 = gB0 + (size_t)16 * K;
  u16* lA0 = &As[w4 * 1024];
  u16* lA1 = &As[w4 * 1024 + 512];
  u16* lB0 = &Bs[w4 * 1024];
  u16* lB1 = &Bs[w4 * 1024 + 512];

  f32x4 acc[4][4] = {};

  for (int k0 = 0; k0 < K; k0 += 32) {
    __syncthreads();
    gload_lds16(gA0 + k0, lA0);
    gload_lds16(gA1 + k0, lA1);
    gload_lds16(gB0 + k0, lB0);
    gload_lds16(gB1 + k0, lB1);
    __syncthreads();

    s16x8 af[4], bf[4];
#pragma unroll
    for (int i = 0; i < 4; i++)
      af[i] = *(const s16x8*)&As[(wm + i * 16 + l15) * 32 + (quad << 3)];
#pragma unroll
    for (int i = 0; i < 4; i++)
      bf[i] = *(const s16x8*)&Bs[(wn + i * 16 + l15) * 32 + (quad << 3)];
#pragma unroll
    for (int mi = 0; mi < 4; mi++)
#pragma unroll
      for (int ni = 0; ni < 4; ni++)
        acc[mi][ni] = __builtin_amdgcn_mfma_f32_16x16x32_bf16(af[mi], bf[ni], acc[mi][ni], 0, 0, 0);
  }

#pragma unroll
  for (int mi = 0; mi < 4; mi++)
#pragma unroll
    for (int ni = 0; ni < 4; ni++)
#pragma unroll
      for (int r = 0; r < 4; r++) {
        int row = m0 + wm + mi * 16 + (quad << 2) + r;
        int col = n0 + wn + ni * 16 + l15;
        float v = acc[mi][ni][r];
        if (writeF32) ((float*)Cout)[(size_t)row * N + col] = v;
        else ((u16*)Cout)[(size_t)row * N + col] = f2b(v);
      }
}

// ---------- in-place RoPE on q (scaled by 0.125) and k ----------
__global__ void rope_kernel(u16* __restrict__ qkv) {
  int row = blockIdx.x;
  int s = row & (S_LEN - 1);
  u16* p = qkv + (size_t)row * NQKV;
  int t = threadIdx.x;
  int d = t & 31;
  int hh = t >> 5;
  float inv_freq = exp2f(-(float)d * (13.287712379549449f / 32.0f));
  float ang = (float)s * inv_freq;
  float sn, cs;
  sincosf(ang, &sn, &cs);
#pragma unroll
  for (int i = 0; i < 4; i++) {
    int base = (hh + (i << 3)) * HEADD + d;
    float x1 = b2f(p[base]);
    float x2 = b2f(p[base + 32]);
    p[base]      = f2b((x1 * cs - x2 * sn) * 0.125f);
    p[base + 32] = f2b((x1 * sn + x2 * cs) * 0.125f);
  }
  {
    int base = DMODEL + hh * HEADD + d;
    float x1 = b2f(p[base]);
    float x2 = b2f(p[base + 32]);
    p[base]      = f2b(x1 * cs - x2 * sn);
    p[base + 32] = f2b(x1 * sn + x2 * cs);
  }
}

// ---------- V transpose: qkv v-slice -> Vt[b][g][d=64][s=2048] ----------
__global__ void vtrans_kernel(const u16* __restrict__ qkv, u16* __restrict__ Vt) {
  __shared__ __align__(16) u16 tile[64][72];
  int bid = blockIdx.x;  // 2*8*32 = 512
  int st = bid & 31;
  int g  = (bid >> 5) & 7;
  int b  = bid >> 8;
  int tid = threadIdx.x;
  int r = tid >> 2;
  int c = (tid & 3) << 4;
  const u16* src = qkv + (size_t)(b * S_LEN + st * 64 + r) * NQKV + 2560 + g * 64 + c;
  *(i32x4*)&tile[r][c]     = *(const i32x4*)src;
  *(i32x4*)&tile[r][c + 8] = *(const i32x4*)(src + 8);
  __syncthreads();
  u16* dst = Vt + (size_t)((b * 8 + g) * 64 + r) * S_LEN + st * 64 + c;
  u16 tmp[16];
#pragma unroll
  for (int j = 0; j < 16; j++) tmp[j] = tile[c + j][r];
  *(i32x4*)dst       = *(i32x4*)&tmp[0];
  *(i32x4*)(dst + 8) = *(i32x4*)&tmp[8];
}

// ---------- MFMA flash attention, 32x32 tiles, lane-local softmax, zero LDS ----------
// 1 wave per block = (b, h, qb). S^T=K*Q^T (q on lane&31); O^T=V^T*P^T (q stays on lane&31).
__global__ __launch_bounds__(64) void attn_kernel(const u16* __restrict__ qkv,
                                                  const u16* __restrict__ Vt,
                                                  u16* __restrict__ out) {
  int bid = blockIdx.x;
  int bh = bid & 63;         // (b,h) in low bits
  int qb = 63 - (bid >> 6);  // longest blocks launch first
  int h = bh & 31;
  int b = bh >> 5;
  int g = h >> 2;
  int lane = threadIdx.x;
  int l31 = lane & 31;
  int h2 = lane >> 5;        // wave half
  int q0 = qb << 5;

  // Q fragments: B-operand layout B[n=q=l31][k = h2*8+j], 4 head-dim steps of 16
  const u16* qp = qkv + (size_t)(b * S_LEN + q0 + l31) * NQKV + h * HEADD + h2 * 8;
  s16x8 qf[4];
#pragma unroll
  for (int t = 0; t < 4; t++) qf[t] = *(const s16x8*)(qp + t * 16);

  const u16* kbase = qkv + ((size_t)(b * S_LEN + l31) * NQKV) + DMODEL + g * HEADD + h2 * 8;
  const u16* vbase = Vt + (size_t)((b * 8 + g) * 64 + l31) * S_LEN + h2 * 8;

  float m_i = -1e30f, l_i = 0.f;
  f32x16 acc[2] = {};

  s16x8 kfa[4], vfa[4], kfb[4], vfb[4];

  auto loadkv = [&](int kb, s16x8 (&kf)[4], s16x8 (&vf)[4]) {
    const u16* kp = kbase + (size_t)kb * 32 * NQKV;
#pragma unroll
    for (int t = 0; t < 4; t++) kf[t] = *(const s16x8*)(kp + t * 16);
    const u16* vp = vbase + kb * 32;
    vf[0] = *(const s16x8*)vp;                           // dt0, s0
    vf[1] = *(const s16x8*)(vp + 16);                    // dt0, s1
    vf[2] = *(const s16x8*)(vp + (size_t)32 * S_LEN);    // dt1, s0
    vf[3] = *(const s16x8*)(vp + (size_t)32 * S_LEN + 16);
  };

  auto compute = [&](int kb, s16x8 (&kf)[4], s16x8 (&vf)[4]) {
    // S^T(32k x 32q): A=K (m=key), B=Q (n=q); 4 steps over head dim
    f32x16 sc = {};
#pragma unroll
    for (int t = 0; t < 4; t++)
      sc = __builtin_amdgcn_mfma_f32_32x32x16_bf16(kf[t], qf[t], sc, 0, 0, 0);

    float sv[16];
#pragma unroll
    for (int j = 0; j < 16; j++) sv[j] = sc[j];

    if (kb == qb) {  // causal mask on the diagonal block (wave-uniform branch)
      int qg = q0 + l31;
#pragma unroll
      for (int j = 0; j < 16; j++) {
        int kg = kb * 32 + (j & 3) + ((j >> 2) << 3) + (h2 << 2);
        if (kg > qg) sv[j] = -1e30f;
      }
    }

    // lane-local softmax for q = l31 (halves combined via one shfl_xor(32))
    float mx = sv[0];
#pragma unroll
    for (int j = 1; j < 16; j++) mx = fmaxf(mx, sv[j]);
    mx = fmaxf(mx, __shfl_xor(mx, 32));
    float m_new = fmaxf(m_i, mx);
    float alpha = __expf(m_i - m_new);
    m_i = m_new;
    float ps = 0.f;
#pragma unroll
    for (int j = 0; j < 16; j++) { sv[j] = __expf(sv[j] - m_new); ps += sv[j]; }
    ps += __shfl_xor(ps, 32);
    l_i = l_i * alpha + ps;

    // pack P pairs to bf16 (half-up rounding), exchange halves, build B-operand frags
    unsigned Pk[8], Ex[8];
#pragma unroll
    for (int r = 0; r < 8; r++) {
      unsigned ae = fbits(sv[2 * r]) + 0x8000u;
      unsigned ao = fbits(sv[2 * r + 1]) + 0x8000u;
      Pk[r] = __builtin_amdgcn_perm(ao, ae, 0x07060302u);  // [lo=even.hi16, hi=odd.hi16]
    }
#pragma unroll
    for (int r = 0; r < 8; r++) Ex[r] = (unsigned)__shfl_xor((int)Pk[r], 32);

    unsigned B0u[4], B1u[4];
    B0u[0] = h2 ? Ex[2] : Pk[0];
    B0u[1] = h2 ? Ex[3] : Pk[1];
    B0u[2] = h2 ? Pk[2] : Ex[0];
    B0u[3] = h2 ? Pk[3] : Ex[1];
    B1u[0] = h2 ? Ex[6] : Pk[4];
    B1u[1] = h2 ? Ex[7] : Pk[5];
    B1u[2] = h2 ? Pk[6] : Ex[4];
    B1u[3] = h2 ? Pk[7] : Ex[5];
    s16x8 B0, B1;
    __builtin_memcpy(&B0, B0u, 16);
    __builtin_memcpy(&B1, B1u, 16);

    // rescale running O^T accumulator (alpha is a lane-scalar: q = l31)
#pragma unroll
    for (int dt = 0; dt < 2; dt++)
#pragma unroll
      for (int j = 0; j < 16; j++) acc[dt][j] *= alpha;

    // O^T += V^T * P^T  (A=V^T: m=d; B=P^T: n=q)
    acc[0] = __builtin_amdgcn_mfma_f32_32x32x16_bf16(vf[0], B0, acc[0], 0, 0, 0);
    acc[0] = __builtin_amdgcn_mfma_f32_32x32x16_bf16(vf[1], B1, acc[0], 0, 0, 0);
    acc[1] = __builtin_amdgcn_mfma_f32_32x32x16_bf16(vf[2], B0, acc[1], 0, 0, 0);
    acc[1] = __builtin_amdgcn_mfma_f32_32x32x16_bf16(vf[3], B1, acc[1], 0, 0, 0);
  };

  loadkv(0, kfa, vfa);
  int kb = 0;
  while (true) {
    if (kb < qb) loadkv(kb + 1, kfb, vfb);
    compute(kb, kfa, vfa);
    if (++kb > qb) break;
    if (kb < qb) loadkv(kb + 1, kfa, vfa);
    compute(kb, kfb, vfb);
    if (++kb > qb) break;
  }

  // epilogue: each lane owns q = q0+l31; d = dt*32 + rg*8 + h2*4 + j
  float linv = 1.0f / l_i;
  u16* op = out + (size_t)(b * S_LEN + q0 + l31) * DMODEL + h * HEADD;
#pragma unroll
  for (int dt = 0; dt < 2; dt++)
#pragma unroll
    for (int rg = 0; rg < 4; rg++) {
      u16x4 t4;
#pragma unroll
      for (int j = 0; j < 4; j++) t4[j] = f2b(acc[dt][rg * 4 + j] * linv);
      *(u16x4*)(op + dt * 32 + rg * 8 + h2 * 4) = t4;
    }
}

extern "C" void kernel_launch(void* const* d_in, const int* in_sizes, int n_in,
                              void* d_out, int out_size, void* d_ws, size_t ws_size,
                              hipStream_t stream) {
  const float* x  = (const float*)d_in[0];
  const float* wq = (const float*)d_in[1];
  const float* wk = (const float*)d_in[2];
  const float* wv = (const float*)d_in[3];
  const float* wo = (const float*)d_in[4];

  char* ws = (char*)d_ws;
  u16* xb    = (u16*)ws;                                   // 4096x2048 bf16 (16.8 MB)
  u16* wqkvT = (u16*)(ws + 16777216);                      // 3072x2048 (12.6 MB)
  u16* woT   = (u16*)(ws + 16777216 + 12582912);           // 2048x2048 (8.4 MB)
  u16* qkv   = (u16*)(ws + 16777216 + 12582912 + 8388608); // 4096x3072 (25.2 MB)
  u16* attnb = xb;     // xb dead after gemm1
  u16* Vt    = wqkvT;  // wqkvT dead after gemm1

  cast_x_kernel<<<8192, 256, 0, stream>>>(x, xb);
  dim3 tb(32, 8);
  transpose_cast<<<dim3(64, 64), tb, 0, stream>>>(wq, wqkvT, 2048, 2048);
  transpose_cast<<<dim3(16, 64), tb, 0, stream>>>(wk, wqkvT + (size_t)2048 * 2048, 512, 2048);
  transpose_cast<<<dim3(16, 64), tb, 0, stream>>>(wv, wqkvT + (size_t)2560 * 2048, 512, 2048);
  transpose_cast<<<dim3(64, 64), tb, 0, stream>>>(wo, woT, 2048, 2048);

  gemm_bt<<<768, 256, 0, stream>>>(xb, wqkvT, qkv, 4096, NQKV, 2048, 0);
  rope_kernel<<<4096, 256, 0, stream>>>(qkv);
  vtrans_kernel<<<512, 256, 0, stream>>>(qkv, Vt);
  attn_kernel<<<4096, 64, 0, stream>>>(qkv, Vt, attnb);
  gemm_bt<<<512, 256, 0, stream>>>(attnb, woT, d_out, 4096, 2048, 2048, 1);
}

// Round 6
// 344.470 us; speedup vs baseline: 14.7898x; 1.1274x over previous
//
#include <hip/hip_runtime.h>

#define S_LEN 2048
#define NH 32
#define NKV 8
#define HEADD 64
#define DMODEL 2048
#define NQKV 3072

typedef float f32x4 __attribute__((ext_vector_type(4)));
typedef float f32x16 __attribute__((ext_vector_type(16)));
typedef short s16x8 __attribute__((ext_vector_type(8)));
typedef int   i32x4 __attribute__((ext_vector_type(4)));
typedef unsigned short u16;
typedef u16 u16x4 __attribute__((ext_vector_type(4)));

__device__ __forceinline__ float b2f(u16 u) {
  unsigned int x = ((unsigned int)u) << 16;
  float f;
  __builtin_memcpy(&f, &x, 4);
  return f;
}
__device__ __forceinline__ u16 f2b(float f) {
  unsigned int x;
  __builtin_memcpy(&x, &f, 4);
  unsigned int r = x + 0x7fffu + ((x >> 16) & 1u);
  return (u16)(r >> 16);
}
__device__ __forceinline__ unsigned fbits(float f) {
  unsigned x; __builtin_memcpy(&x, &f, 4); return x;
}

// async 16B/lane global -> LDS
__device__ __forceinline__ void gload_lds16(const u16* g, u16* l) {
  __builtin_amdgcn_global_load_lds((const __attribute__((address_space(1))) void*)g,
                                   (__attribute__((address_space(3))) void*)l, 16, 0, 0);
}

// ---------- x fp32 -> bf16 ----------
__global__ void cast_x_kernel(const float* __restrict__ src, u16* __restrict__ dst) {
  int i = (blockIdx.x * 256 + threadIdx.x) * 4;
  f32x4 v = *(const f32x4*)(src + i);
  u16x4 o;
  o[0] = f2b(v[0]); o[1] = f2b(v[1]); o[2] = f2b(v[2]); o[3] = f2b(v[3]);
  *(u16x4*)(dst + i) = o;
}

// ---------- transpose + cast: src (K x N fp32) -> dst (N x K bf16) ----------
__global__ void transpose_cast(const float* __restrict__ src, u16* __restrict__ dst, int N, int K) {
  __shared__ float tile[32][33];
  int n0 = blockIdx.x * 32, k0 = blockIdx.y * 32;
  int tx = threadIdx.x, ty = threadIdx.y;  // (32, 8)
#pragma unroll
  for (int i = 0; i < 32; i += 8)
    tile[ty + i][tx] = src[(size_t)(k0 + ty + i) * N + n0 + tx];
  __syncthreads();
#pragma unroll
  for (int i = 0; i < 32; i += 8)
    dst[(size_t)(n0 + ty + i) * K + k0 + tx] = f2b(tile[tx][ty + i]);
}

// ---------- GEMM (m97-style): C(MxN) = A(MxK,bf16) * Bt(NxK,bf16)^T ----------
__global__ __launch_bounds__(256) void gemm_bt(
    const u16* __restrict__ A, const u16* __restrict__ Bt, void* __restrict__ Cout,
    int M, int N, int K, int writeF32) {
  __shared__ __align__(16) u16 As[128 * 32];
  __shared__ __align__(16) u16 Bs[128 * 32];

  int nb = N >> 7;
  int m0 = (blockIdx.x / nb) << 7;
  int n0 = (blockIdx.x % nb) << 7;
  int tid = threadIdx.x;
  int lane = tid & 63;
  int w4 = tid >> 6;
  int l15 = lane & 15;
  int quad = lane >> 4;
  int wm = (w4 >> 1) << 6;
  int wn = (w4 & 1) << 6;

  const u16* gA0 = A  + (size_t)(m0 + w4 * 32 + (lane >> 2)) * K + ((lane & 3) << 3);
  const u16* gA1 = gA0 + (size_t)16 * K;
  const u16* gB0 = Bt + (size_t)(n0 + w4 * 32 + (lane >> 2)) * K + ((lane & 3) << 3);
  const u16* gB1 = gB0 + (size_t)16 * K;
  u16* lA0 = &As[w4 * 1024];
  u16* lA1 = &As[w4 * 1024 + 512];
  u16* lB0 = &Bs[w4 * 1024];
  u16* lB1 = &Bs[w4 * 1024 + 512];

  f32x4 acc[4][4] = {};

  for (int k0 = 0; k0 < K; k0 += 32) {
    __syncthreads();
    gload_lds16(gA0 + k0, lA0);
    gload_lds16(gA1 + k0, lA1);
    gload_lds16(gB0 + k0, lB0);
    gload_lds16(gB1 + k0, lB1);
    __syncthreads();

    s16x8 af[4], bf[4];
#pragma unroll
    for (int i = 0; i < 4; i++)
      af[i] = *(const s16x8*)&As[(wm + i * 16 + l15) * 32 + (quad << 3)];
#pragma unroll
    for (int i = 0; i < 4; i++)
      bf[i] = *(const s16x8*)&Bs[(wn + i * 16 + l15) * 32 + (quad << 3)];
#pragma unroll
    for (int mi = 0; mi < 4; mi++)
#pragma unroll
      for (int ni = 0; ni < 4; ni++)
        acc[mi][ni] = __builtin_amdgcn_mfma_f32_16x16x32_bf16(af[mi], bf[ni], acc[mi][ni], 0, 0, 0);
  }

#pragma unroll
  for (int mi = 0; mi < 4; mi++)
#pragma unroll
    for (int ni = 0; ni < 4; ni++)
#pragma unroll
      for (int r = 0; r < 4; r++) {
        int row = m0 + wm + mi * 16 + (quad << 2) + r;
        int col = n0 + wn + ni * 16 + l15;
        float v = acc[mi][ni][r];
        if (writeF32) ((float*)Cout)[(size_t)row * N + col] = v;
        else ((u16*)Cout)[(size_t)row * N + col] = f2b(v);
      }
}

// ---------- in-place RoPE on q (scaled by 0.125) and k ----------
__global__ void rope_kernel(u16* __restrict__ qkv) {
  int row = blockIdx.x;
  int s = row & (S_LEN - 1);
  u16* p = qkv + (size_t)row * NQKV;
  int t = threadIdx.x;
  int d = t & 31;
  int hh = t >> 5;
  float inv_freq = exp2f(-(float)d * (13.287712379549449f / 32.0f));
  float ang = (float)s * inv_freq;
  float sn, cs;
  sincosf(ang, &sn, &cs);
#pragma unroll
  for (int i = 0; i < 4; i++) {
    int base = (hh + (i << 3)) * HEADD + d;
    float x1 = b2f(p[base]);
    float x2 = b2f(p[base + 32]);
    p[base]      = f2b((x1 * cs - x2 * sn) * 0.125f);
    p[base + 32] = f2b((x1 * sn + x2 * cs) * 0.125f);
  }
  {
    int base = DMODEL + hh * HEADD + d;
    float x1 = b2f(p[base]);
    float x2 = b2f(p[base + 32]);
    p[base]      = f2b(x1 * cs - x2 * sn);
    p[base + 32] = f2b(x1 * sn + x2 * cs);
  }
}

// ---------- V transpose: qkv v-slice -> Vt[b][g][d=64][s=2048] ----------
__global__ void vtrans_kernel(const u16* __restrict__ qkv, u16* __restrict__ Vt) {
  __shared__ __align__(16) u16 tile[64][72];
  int bid = blockIdx.x;  // 2*8*32 = 512
  int st = bid & 31;
  int g  = (bid >> 5) & 7;
  int b  = bid >> 8;
  int tid = threadIdx.x;
  int r = tid >> 2;
  int c = (tid & 3) << 4;
  const u16* src = qkv + (size_t)(b * S_LEN + st * 64 + r) * NQKV + 2560 + g * 64 + c;
  *(i32x4*)&tile[r][c]     = *(const i32x4*)src;
  *(i32x4*)&tile[r][c + 8] = *(const i32x4*)(src + 8);
  __syncthreads();
  u16* dst = Vt + (size_t)((b * 8 + g) * 64 + r) * S_LEN + st * 64 + c;
  u16 tmp[16];
#pragma unroll
  for (int j = 0; j < 16; j++) tmp[j] = tile[c + j][r];
  *(i32x4*)dst       = *(i32x4*)&tmp[0];
  *(i32x4*)(dst + 8) = *(i32x4*)&tmp[8];
}

// ---------- pack K & V into fragment-ordered tiles ----------
// Kp/Vp[(bg*64 + kb)*4 + t][lane][8] : exactly the 16B lane (l31,h2) consumes.
__global__ __launch_bounds__(64) void kvpack_kernel(const u16* __restrict__ qkv,
                                                    const u16* __restrict__ Vt,
                                                    u16* __restrict__ Kp,
                                                    u16* __restrict__ Vp) {
  int bid = blockIdx.x;  // 1024 = bg*64 + kb
  int kb = bid & 63;
  int bg = bid >> 6;
  int g = bg & 7;
  int b = bg >> 3;
  int lane = threadIdx.x;
  int l31 = lane & 31;
  int h2 = lane >> 5;

  const u16* kq = qkv + (size_t)(b * S_LEN + kb * 32 + l31) * NQKV + DMODEL + g * 64 + h2 * 8;
  u16* kdst = Kp + ((size_t)bid * 4) * 512 + lane * 8;
#pragma unroll
  for (int t = 0; t < 4; t++)
    *(i32x4*)(kdst + t * 512) = *(const i32x4*)(kq + t * 16);

  const u16* vq = Vt + (size_t)(bg * 64 + l31) * S_LEN + kb * 32 + h2 * 8;
  u16* vdst = Vp + ((size_t)bid * 4) * 512 + lane * 8;
  *(i32x4*)(vdst)        = *(const i32x4*)vq;
  *(i32x4*)(vdst + 512)  = *(const i32x4*)(vq + 16);
  *(i32x4*)(vdst + 1024) = *(const i32x4*)(vq + (size_t)32 * S_LEN);
  *(i32x4*)(vdst + 1536) = *(const i32x4*)(vq + (size_t)32 * S_LEN + 16);
}

// ---------- MFMA flash attention, 32x32 tiles, packed coalesced K/V, zero LDS ----------
__global__ __launch_bounds__(64) void attn_kernel(const u16* __restrict__ qkv,
                                                  const u16* __restrict__ Kp,
                                                  const u16* __restrict__ Vp,
                                                  u16* __restrict__ out) {
  int bid = blockIdx.x;
  int bh = bid & 63;
  int qb = 63 - (bid >> 6);  // longest blocks launch first
  int h = bh & 31;
  int b = bh >> 5;
  int g = h >> 2;
  int bg = b * 8 + g;
  int lane = threadIdx.x;
  int l31 = lane & 31;
  int h2 = lane >> 5;
  int q0 = qb << 5;

  const u16* qp = qkv + (size_t)(b * S_LEN + q0 + l31) * NQKV + h * HEADD + h2 * 8;
  s16x8 qf[4];
#pragma unroll
  for (int t = 0; t < 4; t++) qf[t] = *(const s16x8*)(qp + t * 16);

  const u16* kp = Kp + ((size_t)bg * 64) * 2048 + lane * 8;  // + kb*2048 + t*512
  const u16* vp = Vp + ((size_t)bg * 64) * 2048 + lane * 8;

  float m_i = -1e30f, l_i = 0.f;
  f32x16 acc[2] = {};

  s16x8 kfa[4], vfa[4], kfb[4], vfb[4];

  auto loadkv = [&](int kb, s16x8 (&kf)[4], s16x8 (&vf)[4]) {
    const u16* kpp = kp + (size_t)kb * 2048;
    const u16* vpp = vp + (size_t)kb * 2048;
#pragma unroll
    for (int t = 0; t < 4; t++) {
      kf[t] = *(const s16x8*)(kpp + t * 512);
      vf[t] = *(const s16x8*)(vpp + t * 512);
    }
  };

  auto compute = [&](int kb, s16x8 (&kf)[4], s16x8 (&vf)[4]) {
    f32x16 sc = {};
#pragma unroll
    for (int t = 0; t < 4; t++)
      sc = __builtin_amdgcn_mfma_f32_32x32x16_bf16(kf[t], qf[t], sc, 0, 0, 0);

    float sv[16];
#pragma unroll
    for (int j = 0; j < 16; j++) sv[j] = sc[j];

    if (kb == qb) {
      int qg = q0 + l31;
#pragma unroll
      for (int j = 0; j < 16; j++) {
        int kg = kb * 32 + (j & 3) + ((j >> 2) << 3) + (h2 << 2);
        if (kg > qg) sv[j] = -1e30f;
      }
    }

    float mx = sv[0];
#pragma unroll
    for (int j = 1; j < 16; j++) mx = fmaxf(mx, sv[j]);
    mx = fmaxf(mx, __shfl_xor(mx, 32));
    float m_new = fmaxf(m_i, mx);
    float alpha = __expf(m_i - m_new);
    m_i = m_new;
    float ps = 0.f;
#pragma unroll
    for (int j = 0; j < 16; j++) { sv[j] = __expf(sv[j] - m_new); ps += sv[j]; }
    ps += __shfl_xor(ps, 32);
    l_i = l_i * alpha + ps;

    unsigned Pk[8], Ex[8];
#pragma unroll
    for (int r = 0; r < 8; r++) {
      unsigned ae = fbits(sv[2 * r]) + 0x8000u;
      unsigned ao = fbits(sv[2 * r + 1]) + 0x8000u;
      Pk[r] = __builtin_amdgcn_perm(ao, ae, 0x07060302u);
    }
#pragma unroll
    for (int r = 0; r < 8; r++) Ex[r] = (unsigned)__shfl_xor((int)Pk[r], 32);

    unsigned B0u[4], B1u[4];
    B0u[0] = h2 ? Ex[2] : Pk[0];
    B0u[1] = h2 ? Ex[3] : Pk[1];
    B0u[2] = h2 ? Pk[2] : Ex[0];
    B0u[3] = h2 ? Pk[3] : Ex[1];
    B1u[0] = h2 ? Ex[6] : Pk[4];
    B1u[1] = h2 ? Ex[7] : Pk[5];
    B1u[2] = h2 ? Pk[6] : Ex[4];
    B1u[3] = h2 ? Pk[7] : Ex[5];
    s16x8 B0, B1;
    __builtin_memcpy(&B0, B0u, 16);
    __builtin_memcpy(&B1, B1u, 16);

#pragma unroll
    for (int dt = 0; dt < 2; dt++)
#pragma unroll
      for (int j = 0; j < 16; j++) acc[dt][j] *= alpha;

    acc[0] = __builtin_amdgcn_mfma_f32_32x32x16_bf16(vf[0], B0, acc[0], 0, 0, 0);
    acc[0] = __builtin_amdgcn_mfma_f32_32x32x16_bf16(vf[1], B1, acc[0], 0, 0, 0);
    acc[1] = __builtin_amdgcn_mfma_f32_32x32x16_bf16(vf[2], B0, acc[1], 0, 0, 0);
    acc[1] = __builtin_amdgcn_mfma_f32_32x32x16_bf16(vf[3], B1, acc[1], 0, 0, 0);
  };

  loadkv(0, kfa, vfa);
  int kb = 0;
  while (true) {
    if (kb < qb) loadkv(kb + 1, kfb, vfb);
    compute(kb, kfa, vfa);
    if (++kb > qb) break;
    if (kb < qb) loadkv(kb + 1, kfa, vfa);
    compute(kb, kfb, vfb);
    if (++kb > qb) break;
  }

  float linv = 1.0f / l_i;
  u16* op = out + (size_t)(b * S_LEN + q0 + l31) * DMODEL + h * HEADD;
#pragma unroll
  for (int dt = 0; dt < 2; dt++)
#pragma unroll
    for (int rg = 0; rg < 4; rg++) {
      u16x4 t4;
#pragma unroll
      for (int j = 0; j < 4; j++) t4[j] = f2b(acc[dt][rg * 4 + j] * linv);
      *(u16x4*)(op + dt * 32 + rg * 8 + h2 * 4) = t4;
    }
}

extern "C" void kernel_launch(void* const* d_in, const int* in_sizes, int n_in,
                              void* d_out, int out_size, void* d_ws, size_t ws_size,
                              hipStream_t stream) {
  const float* x  = (const float*)d_in[0];
  const float* wq = (const float*)d_in[1];
  const float* wk = (const float*)d_in[2];
  const float* wv = (const float*)d_in[3];
  const float* wo = (const float*)d_in[4];

  char* ws = (char*)d_ws;
  u16* xb    = (u16*)ws;                                   // 4096x2048 bf16 (16.8 MB)
  u16* wqkvT = (u16*)(ws + 16777216);                      // 3072x2048 (12.6 MB)
  u16* woT   = (u16*)(ws + 16777216 + 12582912);           // 2048x2048 (8.4 MB)
  u16* qkv   = (u16*)(ws + 16777216 + 12582912 + 8388608); // 4096x3072 (25.2 MB)
  u16* attnb = xb;                                  // xb dead after gemm1
  u16* Vt    = wqkvT;                               // wqkvT region reused after gemm1:
  u16* Kp    = (u16*)(ws + 16777216 + 4194304);     //   Vt(4.2MB) + Kp(4.2MB) + Vp(4.2MB)
  u16* Vp    = (u16*)(ws + 16777216 + 8388608);     //   = 12.6MB (exact fit)

  cast_x_kernel<<<8192, 256, 0, stream>>>(x, xb);
  dim3 tb(32, 8);
  transpose_cast<<<dim3(64, 64), tb, 0, stream>>>(wq, wqkvT, 2048, 2048);
  transpose_cast<<<dim3(16, 64), tb, 0, stream>>>(wk, wqkvT + (size_t)2048 * 2048, 512, 2048);
  transpose_cast<<<dim3(16, 64), tb, 0, stream>>>(wv, wqkvT + (size_t)2560 * 2048, 512, 2048);
  transpose_cast<<<dim3(64, 64), tb, 0, stream>>>(wo, woT, 2048, 2048);

  gemm_bt<<<768, 256, 0, stream>>>(xb, wqkvT, qkv, 4096, NQKV, 2048, 0);
  rope_kernel<<<4096, 256, 0, stream>>>(qkv);
  vtrans_kernel<<<512, 256, 0, stream>>>(qkv, Vt);
  kvpack_kernel<<<1024, 64, 0, stream>>>(qkv, Vt, Kp, Vp);
  attn_kernel<<<4096, 64, 0, stream>>>(qkv, Kp, Vp, attnb);
  gemm_bt<<<512, 256, 0, stream>>>(attnb, woT, d_out, 4096, 2048, 2048, 1);
}